// Round 2
// baseline (1411.157 us; speedup 1.0000x reference)
//
#include <hip/hip_runtime.h>
#include <math.h>

typedef __bf16 bf16x8 __attribute__((ext_vector_type(8)));
typedef float f32x4 __attribute__((ext_vector_type(4)));

#define BM 128
#define BN 128
#define BK 64

__device__ __forceinline__ unsigned short f2bf(float f) {
    union { float f; unsigned u; } x; x.f = f;
    unsigned r = x.u + 0x7FFFu + ((x.u >> 16) & 1u);
    return (unsigned short)(r >> 16);
}

#define GLOAD_LDS16(GP, LP)                                                      \
    __builtin_amdgcn_global_load_lds(                                            \
        (const __attribute__((address_space(1))) unsigned int*)(GP),             \
        (__attribute__((address_space(3))) unsigned int*)(LP), 16, 0, 0)

// C = A * Bt^T (+bias fp32, optional erf-GELU).
// A: [localRows][K] bf16 row-major.  Bt: [E][N][K] bf16 (K contiguous).
// C: bf16 (OUT_F32=false) or fp32 (OUT_F32=true).
// expert e = (groupStart + (blockIdx.y>>4)*eStride) & 7  (2048 rows per group)
// C row remap: rowG = (rowLocal>>11)*groupPitch + (rowLocal&2047)
template <bool GELU, bool OUT_F32>
__global__ __launch_bounds__(256) void gemm_bt(
    const unsigned short* __restrict__ A,
    const unsigned short* __restrict__ Bt,
    const float* __restrict__ bias,
    void* __restrict__ Cv,
    int N, int K, int groupStart, int eStride, int groupPitch)
{
    __shared__ __attribute__((aligned(16))) unsigned short As[BM * BK];
    __shared__ __attribute__((aligned(16))) unsigned short Bs[BN * BK];

    const int tid  = threadIdx.x;
    const int lane = tid & 63;
    const int w    = tid >> 6;
    const int wm   = w & 1;
    const int wn   = w >> 1;

    const int rowBase = blockIdx.y * BM;
    const int colBase = blockIdx.x * BN;
    const int e = (groupStart + (int)(blockIdx.y >> 4) * eStride) & 7;

    const unsigned short* Ag = A + (size_t)(rowBase + w * 8 + (lane >> 3)) * K + (lane & 7) * 8;
    const unsigned short* Bg = Bt + (size_t)e * N * K
                              + (size_t)(colBase + w * 8 + (lane >> 3)) * K + (lane & 7) * 8;

    f32x4 acc[4][4];
    #pragma unroll
    for (int i = 0; i < 4; ++i)
        #pragma unroll
        for (int j = 0; j < 4; ++j)
            acc[i][j] = (f32x4){0.f, 0.f, 0.f, 0.f};

    for (int kt = 0; kt < K; kt += BK) {
        #pragma unroll
        for (int p = 0; p < 4; ++p) {
            GLOAD_LDS16(Ag + (size_t)p * 32 * K + kt, &As[p * 2048 + w * 512]);
            GLOAD_LDS16(Bg + (size_t)p * 32 * K + kt, &Bs[p * 2048 + w * 512]);
        }
        asm volatile("s_waitcnt vmcnt(0)" ::: "memory");
        __syncthreads();

        #pragma unroll
        for (int kb = 0; kb < 2; ++kb) {
            const int lk = kb * 32 + (lane >> 4) * 8;
            const int lr = lane & 15;
            bf16x8 af[4], bfrag[4];
            #pragma unroll
            for (int i = 0; i < 4; ++i)
                af[i] = *(const bf16x8*)&As[(wm * 64 + i * 16 + lr) * BK + lk];
            #pragma unroll
            for (int j = 0; j < 4; ++j)
                bfrag[j] = *(const bf16x8*)&Bs[(wn * 64 + j * 16 + lr) * BK + lk];
            #pragma unroll
            for (int i = 0; i < 4; ++i)
                #pragma unroll
                for (int j = 0; j < 4; ++j)
                    acc[i][j] = __builtin_amdgcn_mfma_f32_16x16x32_bf16(
                        af[i], bfrag[j], acc[i][j], 0, 0, 0);
        }
        __syncthreads();
    }

    // C/D layout: col = lane&15, row = (lane>>4)*4 + reg   [m89]
    const int lr = lane & 15;
    const int lq = lane >> 4;
    const float* be = bias + (size_t)e * N;
    #pragma unroll
    for (int i = 0; i < 4; ++i) {
        #pragma unroll
        for (int r = 0; r < 4; ++r) {
            const int rowLocal = rowBase + wm * 64 + i * 16 + lq * 4 + r;
            const int rowG = (rowLocal >> 11) * groupPitch + (rowLocal & 2047);
            #pragma unroll
            for (int j = 0; j < 4; ++j) {
                const int col = colBase + wn * 64 + j * 16 + lr;
                float v = acc[i][j][r] + be[col];
                if (GELU) v = 0.5f * v * (1.0f + erff(v * 0.70710678118654752f));
                if (OUT_F32)
                    ((float*)Cv)[(size_t)rowG * N + col] = v;
                else
                    ((unsigned short*)Cv)[(size_t)rowG * N + col] = f2bf(v);
            }
        }
    }
}

// W fp32 [R][C] (expert = blockIdx.z) -> Wt bf16 [C][R]
__global__ __launch_bounds__(256) void transpose_cvt(
    const float* __restrict__ W, unsigned short* __restrict__ Wt,
    int R, int C)
{
    __shared__ unsigned short t64[64][68];
    const int t = threadIdx.x;
    const int r0 = blockIdx.y * 64, c0 = blockIdx.x * 64;
    const float* Wp = W + (size_t)blockIdx.z * R * C;
    unsigned short* Wtp = Wt + (size_t)blockIdx.z * R * C;

    #pragma unroll
    for (int p = 0; p < 4; ++p) {
        const int row = p * 16 + (t >> 4);
        const int c4  = (t & 15) * 4;
        float4 v = *(const float4*)&Wp[(size_t)(r0 + row) * C + c0 + c4];
        t64[row][c4 + 0] = f2bf(v.x);
        t64[row][c4 + 1] = f2bf(v.y);
        t64[row][c4 + 2] = f2bf(v.z);
        t64[row][c4 + 3] = f2bf(v.w);
    }
    __syncthreads();
    #pragma unroll
    for (int p = 0; p < 4; ++p) {
        const int oc = p * 16 + (t >> 4);
        const int r4 = (t & 15) * 4;
        ushort4 o;
        o.x = t64[r4 + 0][oc];
        o.y = t64[r4 + 1][oc];
        o.z = t64[r4 + 2][oc];
        o.w = t64[r4 + 3][oc];
        *(ushort4*)&Wtp[(size_t)(c0 + oc) * R + r0 + r4] = o;
    }
}

__global__ __launch_bounds__(256) void cvt_f32_bf16(
    const float* __restrict__ in, unsigned short* __restrict__ out, long long n)
{
    long long i = ((long long)blockIdx.x * 256 + threadIdx.x) * 4;
    if (i < n) {
        float4 v = *(const float4*)&in[i];
        ushort4 o;
        o.x = f2bf(v.x); o.y = f2bf(v.y); o.z = f2bf(v.z); o.w = f2bf(v.w);
        *(ushort4*)&out[i] = o;
    }
}

extern "C" void kernel_launch(void* const* d_in, const int* in_sizes, int n_in,
                              void* d_out, int out_size, void* d_ws, size_t ws_size,
                              hipStream_t stream) {
    const float* x  = (const float*)d_in[0];
    const float* w1 = (const float*)d_in[1];
    const float* b1 = (const float*)d_in[2];
    const float* w2 = (const float*)d_in[3];
    const float* b2 = (const float*)d_in[4];
    float* out = (float*)d_out;
    unsigned short* ws = (unsigned short*)d_ws;

    const int E = 8, D = 1024, F = 4096, Bdim = 2, Cap = 2048;
    const int T = E * Cap;                       // 16384
    const size_t xbE = (size_t)Bdim * T * D;     // 33,554,432
    const size_t wE  = (size_t)E * D * F;        // 33,554,432
    const size_t gE  = (size_t)Cap * F;          // 8,388,608 (H elems per group)

    dim3 blk(256);
    const size_t fullBytes = (xbE + 2 * wE + gE) * 2;   // 218,103,808

    if (ws_size >= fullBytes) {
        // FULL path: everything converted once, groups batched.
        unsigned short* xb  = ws;
        unsigned short* w1t = ws + xbE;
        unsigned short* w2t = ws + xbE + wE;
        unsigned short* H   = ws + xbE + 2 * wE;
        int gpc = (int)((ws_size / 2 - (xbE + 2 * wE)) / gE);
        if (gpc > 16) gpc = 16;
        if (gpc < 1)  gpc = 1;

        cvt_f32_bf16<<<(unsigned)((xbE / 4 + 255) / 256), blk, 0, stream>>>(x, xb, (long long)xbE);
        transpose_cvt<<<dim3(F / 64, D / 64, E), blk, 0, stream>>>(w1, w1t, D, F);
        transpose_cvt<<<dim3(D / 64, F / 64, E), blk, 0, stream>>>(w2, w2t, F, D);

        for (int g0 = 0; g0 < Bdim * E; g0 += gpc) {
            const int ng = (g0 + gpc <= Bdim * E) ? gpc : (Bdim * E - g0);
            gemm_bt<true, false><<<dim3(F / BN, ng * 16), blk, 0, stream>>>(
                xb + (size_t)g0 * Cap * D, w1t, b1, H, F, D, g0, 1, 2048);
            gemm_bt<false, true><<<dim3(D / BN, ng * 16), blk, 0, stream>>>(
                H, w2t, b2, out + (size_t)g0 * Cap * D, D, F, g0, 1, 2048);
        }
    } else {
        // LEAN path: per-expert, both b-groups batched.  ~59 MB of ws.
        unsigned short* w1t = ws;                               // F*D
        unsigned short* w2t = w1t + (size_t)F * D;              // D*F
        unsigned short* xb  = w2t + (size_t)D * F;              // 2*Cap*D
        unsigned short* H   = xb + 2 * (size_t)Cap * D;         // 2*Cap*F

        for (int e = 0; e < E; ++e) {
            transpose_cvt<<<dim3(F / 64, D / 64, 1), blk, 0, stream>>>(
                w1 + (size_t)e * D * F, w1t, D, F);
            transpose_cvt<<<dim3(D / 64, F / 64, 1), blk, 0, stream>>>(
                w2 + (size_t)e * F * D, w2t, F, D);
            for (int b = 0; b < Bdim; ++b)
                cvt_f32_bf16<<<(unsigned)(((size_t)Cap * D / 4 + 255) / 256), blk, 0, stream>>>(
                    x + ((size_t)b * T + (size_t)e * Cap) * D,
                    xb + (size_t)b * Cap * D, (long long)Cap * D);
            gemm_bt<true, false><<<dim3(F / BN, 32), blk, 0, stream>>>(
                xb, w1t, b1, H, F, D, e, 0, 2048);
            gemm_bt<false, true><<<dim3(D / BN, 32), blk, 0, stream>>>(
                H, w2t, b2, out + (size_t)e * Cap * D, D, F, e, 0, T);
        }
    }
}

// Round 3
// 1088.103 us; speedup vs baseline: 1.2969x; 1.2969x over previous
//
#include <hip/hip_runtime.h>
#include <math.h>

typedef __bf16 bf16x8 __attribute__((ext_vector_type(8)));
typedef float f32x4 __attribute__((ext_vector_type(4)));

#define BM 128
#define BN 128
#define BK 64

__device__ __forceinline__ unsigned short f2bf(float f) {
    union { float f; unsigned u; } x; x.f = f;
    unsigned r = x.u + 0x7FFFu + ((x.u >> 16) & 1u);
    return (unsigned short)(r >> 16);
}

// erf-GELU via Abramowitz-Stegun 7.1.26 (|err| <= 1.5e-7), branchless.
__device__ __forceinline__ float fast_gelu(float h) {
    const float z  = __builtin_fabsf(h) * 0.70710678118654752f;
    const float t  = __builtin_amdgcn_rcpf(__builtin_fmaf(0.3275911f, z, 1.0f));
    float p = 1.061405429f;
    p = __builtin_fmaf(p, t, -1.453152027f);
    p = __builtin_fmaf(p, t,  1.421413741f);
    p = __builtin_fmaf(p, t, -0.284496736f);
    p = __builtin_fmaf(p, t,  0.254829592f);
    const float ez = __builtin_amdgcn_exp2f(-z * z * 1.4426950408889634f);
    float erfz = __builtin_fmaf(-p * t, ez, 1.0f);
    erfz = (h < 0.0f) ? -erfz : erfz;
    return 0.5f * h * (1.0f + erfz);
}

#define GLOAD_LDS16(GP, LP)                                                      \
    __builtin_amdgcn_global_load_lds(                                            \
        (const __attribute__((address_space(1))) unsigned int*)(GP),             \
        (__attribute__((address_space(3))) unsigned int*)(LP), 16, 0, 0)

// C = A * Bt^T (+bias fp32, optional erf-GELU).
// A: [localRows][K] bf16 row-major.  Bt: [E][N][K] bf16 (K contiguous).
// LDS tiles are XOR-swizzled: physical 16B-chunk pc of row r holds global
// chunk pc ^ (r&7)  (applied via the staging lane's global address; the
// global_load_lds LDS destination is fixed at base + lane*16).
template <bool GELU, bool OUT_F32>
__global__ __launch_bounds__(256) void gemm_bt(
    const unsigned short* __restrict__ A,
    const unsigned short* __restrict__ Bt,
    const float* __restrict__ bias,
    void* __restrict__ Cv,
    int N, int K, int groupStart, int eStride, int groupPitch)
{
    __shared__ __attribute__((aligned(16))) unsigned short As[BM * BK];
    __shared__ __attribute__((aligned(16))) unsigned short Bs[BN * BK];

    const int tid  = threadIdx.x;
    const int lane = tid & 63;
    const int w    = tid >> 6;
    const int wm   = w & 1;
    const int wn   = w >> 1;

    const int rowBase = blockIdx.y * BM;
    const int colBase = blockIdx.x * BN;
    const int e = (groupStart + (int)(blockIdx.y >> 4) * eStride) & 7;

    // Staging: lane covers physical (row = p*32 + w*8 + lane>>3, chunk = lane&7);
    // its global k-chunk is swizzled: (lane&7) ^ (lane>>3).
    const int swzChunk = ((lane & 7) ^ (lane >> 3)) * 8;  // in shorts
    const unsigned short* Ag = A + (size_t)(rowBase + w * 8 + (lane >> 3)) * K + swzChunk;
    const unsigned short* Bg = Bt + (size_t)e * N * K
                              + (size_t)(colBase + w * 8 + (lane >> 3)) * K + swzChunk;

    f32x4 acc[4][4];
    #pragma unroll
    for (int i = 0; i < 4; ++i)
        #pragma unroll
        for (int j = 0; j < 4; ++j)
            acc[i][j] = (f32x4){0.f, 0.f, 0.f, 0.f};

    const int lr = lane & 15;
    const int q  = lane >> 4;

    for (int kt = 0; kt < K; kt += BK) {
        #pragma unroll
        for (int p = 0; p < 4; ++p) {
            GLOAD_LDS16(Ag + (size_t)p * 32 * K + kt, &As[p * 2048 + w * 512]);
            GLOAD_LDS16(Bg + (size_t)p * 32 * K + kt, &Bs[p * 2048 + w * 512]);
        }
        asm volatile("s_waitcnt vmcnt(0)" ::: "memory");
        __syncthreads();

        #pragma unroll
        for (int kb = 0; kb < 2; ++kb) {
            // un-swizzle: want global chunk kb*4+q of row; it lives at
            // physical chunk (kb*4+q) ^ (row&7),  row&7 == lr&7.
            const int pc = ((kb * 4 + q) ^ (lr & 7)) * 8;   // in shorts
            bf16x8 af[4], bfrag[4];
            #pragma unroll
            for (int i = 0; i < 4; ++i)
                af[i] = *(const bf16x8*)&As[(wm * 64 + i * 16 + lr) * BK + pc];
            #pragma unroll
            for (int j = 0; j < 4; ++j)
                bfrag[j] = *(const bf16x8*)&Bs[(wn * 64 + j * 16 + lr) * BK + pc];
            #pragma unroll
            for (int i = 0; i < 4; ++i)
                #pragma unroll
                for (int j = 0; j < 4; ++j)
                    acc[i][j] = __builtin_amdgcn_mfma_f32_16x16x32_bf16(
                        af[i], bfrag[j], acc[i][j], 0, 0, 0);
        }
        __syncthreads();
    }

    // Epilogue.  C/D layout: col = lane&15, row = (lane>>4)*4 + reg   [m89]
    const float* be = bias + (size_t)e * N;
    float bj[4];
    #pragma unroll
    for (int j = 0; j < 4; ++j)
        bj[j] = be[colBase + wn * 64 + j * 16 + lr];

    #pragma unroll
    for (int i = 0; i < 4; ++i) {
        #pragma unroll
        for (int r = 0; r < 4; ++r) {
            const int rowLocal = rowBase + wm * 64 + i * 16 + q * 4 + r;
            const int rowG = (rowLocal >> 11) * groupPitch + (rowLocal & 2047);
            #pragma unroll
            for (int j = 0; j < 4; ++j) {
                const int col = colBase + wn * 64 + j * 16 + lr;
                float v = acc[i][j][r] + bj[j];
                if (GELU) v = fast_gelu(v);
                if (OUT_F32)
                    ((float*)Cv)[(size_t)rowG * N + col] = v;
                else
                    ((unsigned short*)Cv)[(size_t)rowG * N + col] = f2bf(v);
            }
        }
    }
}

// W fp32 [R][C] (expert = blockIdx.z) -> Wt bf16 [C][R]
__global__ __launch_bounds__(256) void transpose_cvt(
    const float* __restrict__ W, unsigned short* __restrict__ Wt,
    int R, int C)
{
    __shared__ unsigned short t64[64][68];
    const int t = threadIdx.x;
    const int r0 = blockIdx.y * 64, c0 = blockIdx.x * 64;
    const float* Wp = W + (size_t)blockIdx.z * R * C;
    unsigned short* Wtp = Wt + (size_t)blockIdx.z * R * C;

    #pragma unroll
    for (int p = 0; p < 4; ++p) {
        const int row = p * 16 + (t >> 4);
        const int c4  = (t & 15) * 4;
        float4 v = *(const float4*)&Wp[(size_t)(r0 + row) * C + c0 + c4];
        t64[row][c4 + 0] = f2bf(v.x);
        t64[row][c4 + 1] = f2bf(v.y);
        t64[row][c4 + 2] = f2bf(v.z);
        t64[row][c4 + 3] = f2bf(v.w);
    }
    __syncthreads();
    #pragma unroll
    for (int p = 0; p < 4; ++p) {
        const int oc = p * 16 + (t >> 4);
        const int r4 = (t & 15) * 4;
        ushort4 o;
        o.x = t64[r4 + 0][oc];
        o.y = t64[r4 + 1][oc];
        o.z = t64[r4 + 2][oc];
        o.w = t64[r4 + 3][oc];
        *(ushort4*)&Wtp[(size_t)(c0 + oc) * R + r0 + r4] = o;
    }
}

__global__ __launch_bounds__(256) void cvt_f32_bf16(
    const float* __restrict__ in, unsigned short* __restrict__ out, long long n)
{
    long long i = ((long long)blockIdx.x * 256 + threadIdx.x) * 4;
    if (i < n) {
        float4 v = *(const float4*)&in[i];
        ushort4 o;
        o.x = f2bf(v.x); o.y = f2bf(v.y); o.z = f2bf(v.z); o.w = f2bf(v.w);
        *(ushort4*)&out[i] = o;
    }
}

extern "C" void kernel_launch(void* const* d_in, const int* in_sizes, int n_in,
                              void* d_out, int out_size, void* d_ws, size_t ws_size,
                              hipStream_t stream) {
    const float* x  = (const float*)d_in[0];
    const float* w1 = (const float*)d_in[1];
    const float* b1 = (const float*)d_in[2];
    const float* w2 = (const float*)d_in[3];
    const float* b2 = (const float*)d_in[4];
    float* out = (float*)d_out;
    unsigned short* ws = (unsigned short*)d_ws;

    const int E = 8, D = 1024, F = 4096, Bdim = 2, Cap = 2048;
    const int T = E * Cap;                       // 16384
    const size_t xbE = (size_t)Bdim * T * D;     // 33,554,432
    const size_t wE  = (size_t)E * D * F;        // 33,554,432
    const size_t gE  = (size_t)Cap * F;          // 8,388,608 (H elems per group)

    dim3 blk(256);
    const size_t fullBytes = (xbE + 2 * wE + gE) * 2;   // 218,103,808

    if (ws_size >= fullBytes) {
        // FULL path: everything converted once, groups batched.
        unsigned short* xb  = ws;
        unsigned short* w1t = ws + xbE;
        unsigned short* w2t = ws + xbE + wE;
        unsigned short* H   = ws + xbE + 2 * wE;
        int gpc = (int)((ws_size / 2 - (xbE + 2 * wE)) / gE);
        if (gpc > 16) gpc = 16;
        if (gpc < 1)  gpc = 1;

        cvt_f32_bf16<<<(unsigned)((xbE / 4 + 255) / 256), blk, 0, stream>>>(x, xb, (long long)xbE);
        transpose_cvt<<<dim3(F / 64, D / 64, E), blk, 0, stream>>>(w1, w1t, D, F);
        transpose_cvt<<<dim3(D / 64, F / 64, E), blk, 0, stream>>>(w2, w2t, F, D);

        for (int g0 = 0; g0 < Bdim * E; g0 += gpc) {
            const int ng = (g0 + gpc <= Bdim * E) ? gpc : (Bdim * E - g0);
            gemm_bt<true, false><<<dim3(F / BN, ng * 16), blk, 0, stream>>>(
                xb + (size_t)g0 * Cap * D, w1t, b1, H, F, D, g0, 1, 2048);
            gemm_bt<false, true><<<dim3(D / BN, ng * 16), blk, 0, stream>>>(
                H, w2t, b2, out + (size_t)g0 * Cap * D, D, F, g0, 1, 2048);
        }
    } else {
        // LEAN path: per-expert, both b-groups batched.  ~59 MB of ws.
        unsigned short* w1t = ws;                               // F*D
        unsigned short* w2t = w1t + (size_t)F * D;              // D*F
        unsigned short* xb  = w2t + (size_t)D * F;              // 2*Cap*D
        unsigned short* H   = xb + 2 * (size_t)Cap * D;         // 2*Cap*F

        for (int e = 0; e < E; ++e) {
            transpose_cvt<<<dim3(F / 64, D / 64, 1), blk, 0, stream>>>(
                w1 + (size_t)e * D * F, w1t, D, F);
            transpose_cvt<<<dim3(D / 64, F / 64, 1), blk, 0, stream>>>(
                w2 + (size_t)e * F * D, w2t, F, D);
            for (int b = 0; b < Bdim; ++b)
                cvt_f32_bf16<<<(unsigned)(((size_t)Cap * D / 4 + 255) / 256), blk, 0, stream>>>(
                    x + ((size_t)b * T + (size_t)e * Cap) * D,
                    xb + (size_t)b * Cap * D, (long long)Cap * D);
            gemm_bt<true, false><<<dim3(F / BN, 32), blk, 0, stream>>>(
                xb, w1t, b1, H, F, D, e, 0, 2048);
            gemm_bt<false, true><<<dim3(D / BN, 32), blk, 0, stream>>>(
                H, w2t, b2, out + (size_t)e * Cap * D, D, F, e, 0, T);
        }
    }
}